// Round 11
// baseline (177.842 us; speedup 1.0000x reference)
//
#include <hip/hip_runtime.h>
#include <hip/hip_bf16.h>

#define BB 4
#define TT 2048
#define DIM 512
#define NH 8
#define HD 64
#define NROW (BB*TT)   // 8192
#define BH (BB*NH)     // 32

typedef unsigned short u16;
typedef unsigned int u32;
typedef __attribute__((ext_vector_type(8))) short bf16x8;   // 8 bf16 = 4 VGPRs
typedef __attribute__((ext_vector_type(8))) unsigned short u16x8;
typedef __attribute__((ext_vector_type(4))) float f32x4;
typedef __attribute__((ext_vector_type(16))) float f32x16;
typedef __attribute__((ext_vector_type(4))) unsigned short u16x4;
typedef __attribute__((ext_vector_type(2))) unsigned int u32x2;

static __device__ __forceinline__ float bf2f(u16 u) {
    return __uint_as_float(((u32)u) << 16);
}
static __device__ __forceinline__ u16 f2bf(float f) {
    u32 u = __float_as_uint(f);
    u32 r = (u + 0x7FFFu + ((u >> 16) & 1u)) >> 16;
    return (u16)r;
}
// packed f32x2 -> bf16x2 (v_cvt_pk_bf16_f32 on gfx950)
static __device__ __forceinline__ u32 cvtpk(float a, float b) {
    union { __hip_bfloat162 h2; u32 u; } cv;
    cv.h2 = __float22bfloat162_rn(make_float2(a, b));
    return cv.u;
}
// async global -> LDS, 16B per lane. LDS dest = wave-uniform base + lane*16.
static __device__ __forceinline__ void gll16(const u16* g, u16* l) {
    __builtin_amdgcn_global_load_lds(
        (const __attribute__((address_space(1))) unsigned int*)g,
        (__attribute__((address_space(3))) unsigned int*)l,
        16, 0, 0);
}

// ---------------- prep: fused convert_x (blocks 0..255) + W transposes
__global__ __launch_bounds__(256) void prep_kernel(
    const float* __restrict__ x, u16* __restrict__ x16, u32* __restrict__ bmaxsq,
    const float* __restrict__ Wqkv, u16* __restrict__ Wtq,
    const float* __restrict__ Wproj, u16* __restrict__ Wtp)
{
    const int bid = blockIdx.x;
    const int tid = threadIdx.x;
    __shared__ u16 t[32][33];
    __shared__ float red[4];

    if (bid < 256) {
        const int row = bid * 32 + (tid >> 3);
        const int b = (bid * 32) >> 11;
        const float* xr = x   + (size_t)row * DIM + (tid & 7) * 64;
        u16*        xo  = x16 + (size_t)row * DIM + (tid & 7) * 64;
        float s = 0.0f;
        #pragma unroll
        for (int j = 0; j < 8; ++j) {
            float4 a = *(const float4*)(xr + j*8);
            float4 c = *(const float4*)(xr + j*8 + 4);
            s += a.x*a.x + a.y*a.y + a.z*a.z + a.w*a.w;
            s += c.x*c.x + c.y*c.y + c.z*c.z + c.w*c.w;
            u16x8 pk;
            pk[0]=f2bf(a.x); pk[1]=f2bf(a.y); pk[2]=f2bf(a.z); pk[3]=f2bf(a.w);
            pk[4]=f2bf(c.x); pk[5]=f2bf(c.y); pk[6]=f2bf(c.z); pk[7]=f2bf(c.w);
            *(u16x8*)(xo + j*8) = pk;
        }
        #pragma unroll
        for (int off = 1; off < 8; off <<= 1) s += __shfl_xor(s, off, 64);
        float m = s;
        #pragma unroll
        for (int off = 8; off < 64; off <<= 1) m = fmaxf(m, __shfl_xor(m, off, 64));
        if ((tid & 63) == 0) red[tid >> 6] = m;
        __syncthreads();
        if (tid == 0) {
            float mx = fmaxf(fmaxf(red[0], red[1]), fmaxf(red[2], red[3]));
            atomicMax(&bmaxsq[b], __float_as_uint(mx));
        }
    } else {
        const float* in; u16* outp; int K, N, tb;
        if (bid < 768) { in = Wqkv; outp = Wtq; K = 512; N = 1024; tb = bid - 256; }
        else           { in = Wproj; outp = Wtp; K = 512; N = 512;  tb = bid - 768; }
        const int ntiles = N >> 5;
        const int bx = tb % ntiles, by = tb / ntiles;
        const int n0 = bx * 32, k0 = by * 32;
        const int tx = tid & 31, ty = tid >> 5;
        #pragma unroll
        for (int i = 0; i < 32; i += 8)
            t[ty + i][tx] = f2bf(in[(size_t)(k0 + ty + i) * N + n0 + tx]);
        __syncthreads();
        #pragma unroll
        for (int i = 0; i < 32; i += 8)
            outp[(size_t)(n0 + ty + i) * K + k0 + tx] = t[tx][ty + i];
    }
}

// ---------------- MFMA GEMM: qkv = x16 @ Wqkv (via Wt [1024][512] bf16)
// v5: dbuf gll16 staging (vmcnt(8)) + LDS-transposed coalesced epilogue
// + FUSED qsq/asq: the q-store loop holds exactly this block's 8 d-values
// per (h,t) -> square-sum + 1 coalesced atomicAdd/thread to qsq (8-way
// contention), wave-uniform-h shuffle reduce + 1 atomic/wave to asq.
// Replaces the whole qsq_kernel (8MB re-read + launch gap).
__global__ __launch_bounds__(256) void qkv_mfma(
    const u16* __restrict__ x16, const u16* __restrict__ Wt,
    u16* __restrict__ q16, u16* __restrict__ vt16,
    float* __restrict__ qsq, float* __restrict__ asq)
{
    const int tid = threadIdx.x, lane = tid & 63, w = tid >> 6;
    const int li = lane & 15, quad = lane >> 4;
    const int mb = blockIdx.x >> 3, nb = blockIdx.x & 7;   // 64 x 8
    const int row0 = mb * 128, n0 = nb * 128;
    const int b = row0 >> 11;
    const int wm = w >> 1, wn = w & 1;

    __shared__ __align__(16) u16 smemq[32768];   // 64KB: staging + epilogue
    u16* as0 = smemq;            // [2][8192] A bufs
    u16* bs0 = smemq + 16384;    // [2][8192] B bufs

    const int rstg = tid >> 3;
    const int cstg = ((tid & 7) ^ (rstg & 7)) * 8;
    const u16* xa = x16 + (size_t)(row0 + rstg) * DIM + cstg;
    const u16* wb = Wt  + (size_t)(n0  + rstg) * DIM + cstg;
    const int ldb = w * 512;                               // wave-uniform base

    const int fs0 = ((quad)     ^ (li & 7)) << 3;
    const int fs1 = ((quad + 4) ^ (li & 7)) << 3;

    auto stage = [&](int bf, int k0) {
        #pragma unroll
        for (int it = 0; it < 4; ++it) {
            gll16(xa + k0 + (size_t)it * 32 * DIM, as0 + bf*8192 + it*2048 + ldb);
            gll16(wb + k0 + (size_t)it * 32 * DIM, bs0 + bf*8192 + it*2048 + ldb);
        }
    };

    f32x4 acc[4][4];
    #pragma unroll
    for (int mi = 0; mi < 4; ++mi)
        #pragma unroll
        for (int ni = 0; ni < 4; ++ni) acc[mi][ni] = f32x4{0.f,0.f,0.f,0.f};

    stage(0, 0);
    for (int ki = 0; ki < 8; ++ki) {
        const int cur = ki & 1;
        if (ki < 7) {
            stage(cur ^ 1, (ki + 1) * 64);
            asm volatile("s_waitcnt vmcnt(8)" ::: "memory");
        } else {
            asm volatile("s_waitcnt vmcnt(0)" ::: "memory");
        }
        __syncthreads();

        bf16x8 af[4][2], bfr[4][2];
        #pragma unroll
        for (int mi = 0; mi < 4; ++mi) {
            const u16* p = &as0[cur*8192 + (wm*64 + mi*16 + li) * 64];
            af[mi][0] = *(const bf16x8*)(p + fs0);
            af[mi][1] = *(const bf16x8*)(p + fs1);
        }
        #pragma unroll
        for (int ni = 0; ni < 4; ++ni) {
            const u16* p = &bs0[cur*8192 + (wn*64 + ni*16 + li) * 64];
            bfr[ni][0] = *(const bf16x8*)(p + fs0);
            bfr[ni][1] = *(const bf16x8*)(p + fs1);
        }
        #pragma unroll
        for (int mi = 0; mi < 4; ++mi)
            #pragma unroll
            for (int ni = 0; ni < 4; ++ni) {
                acc[mi][ni] = __builtin_amdgcn_mfma_f32_16x16x32_bf16(
                    af[mi][0], bfr[ni][0], acc[mi][ni], 0, 0, 0);
                acc[mi][ni] = __builtin_amdgcn_mfma_f32_16x16x32_bf16(
                    af[mi][1], bfr[ni][1], acc[mi][ni], 0, 0, 0);
            }
        __syncthreads();
    }

    // ---- epilogue: acc -> LDS [c_local 128][t 128] bf16 (stride 132) ----
    u16* eps = smemq;   // 128*132*2 = 33792 B, staging fully consumed
    const int cbase = wn*64 + li;
    const int tbase = wm*64 + quad*4;
    #pragma unroll
    for (int ni = 0; ni < 4; ++ni)
        #pragma unroll
        for (int mi = 0; mi < 4; ++mi) {
            union { u32 u[2]; u16x4 v; } pk;
            pk.u[0] = cvtpk(acc[mi][ni][0], acc[mi][ni][1]);
            pk.u[1] = cvtpk(acc[mi][ni][2], acc[mi][ni][3]);
            *(u16x4*)&eps[(cbase + ni*16)*132 + tbase + mi*16] = pk.v;
        }
    __syncthreads();

    const int trow = row0 & (TT-1);
    const int d0 = n0 >> 4;
    // q: c_local = dl*16 + h (k=0). Chunk (h,t): gather 8 u16 -> 16B store
    // + fused qsq partial (this block's 8 d-values for that (h,t)).
    #pragma unroll
    for (int it = 0; it < 4; ++it) {
        int id = it*256 + tid;
        int h = id >> 7, t = id & 127;          // h is wave-uniform per it
        union { u16 a[8]; u16x8 v; } ch;
        float qs = 0.0f;
        #pragma unroll
        for (int dl = 0; dl < 8; ++dl) {
            ch.a[dl] = eps[(dl*16 + h)*132 + t];
            float f = bf2f(ch.a[dl]);
            qs = fmaf(f, f, qs);
        }
        *(u16x8*)(q16 + ((size_t)(b*NH + h)*TT + trow + t)*HD + d0) = ch.v;
        atomicAdd(&qsq[(size_t)(b*NH + h)*TT + trow + t], qs);
        // asq: wave-reduce (h uniform within wave) + one atomic per wave
        float ws_ = qs;
        #pragma unroll
        for (int off = 32; off > 0; off >>= 1) ws_ += __shfl_down(ws_, off, 64);
        if (lane == 0) atomicAdd(&asq[b*NH + h], ws_);
    }
    // v: c_local = dl*16 + 8 + h (k=1). Row-contig LDS -> coalesced 16B.
    #pragma unroll
    for (int it = 0; it < 4; ++it) {
        int id = it*256 + tid;
        int tc = id & 15, dl = (id >> 4) & 7, h = id >> 7;
        union { u16x4 a[2]; u16x8 v; } ch;
        ch.a[0] = *(const u16x4*)&eps[(dl*16 + 8 + h)*132 + tc*8];
        ch.a[1] = *(const u16x4*)&eps[(dl*16 + 8 + h)*132 + tc*8 + 4];
        *(u16x8*)(vt16 + ((size_t)(b*NH + h)*HD + d0 + dl)*TT + trow + tc*8) = ch.v;
    }
}

// ---------------- MFMA GEMM: out(f32) = ao16 @ Wproj + bias(f32)
// v3: N-tile 64 (grid 512 -> 2 blocks/CU), dbuf gll16 staging, vmcnt(6).
__global__ __launch_bounds__(256) void proj_mfma(
    const u16* __restrict__ ao16, const u16* __restrict__ Wt,
    const float* __restrict__ bp, float* __restrict__ out)
{
    const int tid = threadIdx.x, lane = tid & 63, w = tid >> 6;
    const int li = lane & 15, quad = lane >> 4;
    const int mb = blockIdx.x >> 3, nb = blockIdx.x & 7;   // 64 x 8
    const int row0 = mb * 128, n0 = nb * 64;
    const int wm = w >> 1, wn = w & 1;

    __shared__ __align__(16) u16 as[2][128 * 64];
    __shared__ __align__(16) u16 bs[2][64 * 64];

    const int rstg = tid >> 3;
    const int cstg = ((tid & 7) ^ (rstg & 7)) * 8;
    const u16* xa = ao16 + (size_t)(row0 + rstg) * DIM + cstg;
    const u16* wb = Wt   + (size_t)(n0  + rstg) * DIM + cstg;
    const int ldb = w * 512;

    const int fs0 = ((quad)     ^ (li & 7)) << 3;
    const int fs1 = ((quad + 4) ^ (li & 7)) << 3;

    auto stage = [&](int bf, int k0) {
        #pragma unroll
        for (int it = 0; it < 4; ++it)
            gll16(xa + k0 + (size_t)it * 32 * DIM, &as[bf][0] + it * 2048 + ldb);
        #pragma unroll
        for (int it = 0; it < 2; ++it)
            gll16(wb + k0 + (size_t)it * 32 * DIM, &bs[bf][0] + it * 2048 + ldb);
    };

    f32x4 acc[4][2];
    #pragma unroll
    for (int mi = 0; mi < 4; ++mi)
        #pragma unroll
        for (int ni = 0; ni < 2; ++ni) acc[mi][ni] = f32x4{0.f,0.f,0.f,0.f};

    stage(0, 0);
    for (int ki = 0; ki < 8; ++ki) {
        const int cur = ki & 1;
        if (ki < 7) {
            stage(cur ^ 1, (ki + 1) * 64);
            asm volatile("s_waitcnt vmcnt(6)" ::: "memory");
        } else {
            asm volatile("s_waitcnt vmcnt(0)" ::: "memory");
        }
        __syncthreads();

        bf16x8 af[4][2], bfr[2][2];
        #pragma unroll
        for (int mi = 0; mi < 4; ++mi) {
            const u16* p = &as[cur][(wm*64 + mi*16 + li) * 64];
            af[mi][0] = *(const bf16x8*)(p + fs0);
            af[mi][1] = *(const bf16x8*)(p + fs1);
        }
        #pragma unroll
        for (int ni = 0; ni < 2; ++ni) {
            const u16* p = &bs[cur][(wn*32 + ni*16 + li) * 64];
            bfr[ni][0] = *(const bf16x8*)(p + fs0);
            bfr[ni][1] = *(const bf16x8*)(p + fs1);
        }
        #pragma unroll
        for (int mi = 0; mi < 4; ++mi)
            #pragma unroll
            for (int ni = 0; ni < 2; ++ni) {
                acc[mi][ni] = __builtin_amdgcn_mfma_f32_16x16x32_bf16(
                    af[mi][0], bfr[ni][0], acc[mi][ni], 0, 0, 0);
                acc[mi][ni] = __builtin_amdgcn_mfma_f32_16x16x32_bf16(
                    af[mi][1], bfr[ni][1], acc[mi][ni], 0, 0, 0);
            }
        __syncthreads();
    }

    #pragma unroll
    for (int ni = 0; ni < 2; ++ni) {
        int col = n0 + wn*32 + ni*16 + li;
        float bias = bp[col];
        #pragma unroll
        for (int mi = 0; mi < 4; ++mi) {
            int r0 = row0 + wm*64 + mi*16 + quad*4;
            #pragma unroll
            for (int r = 0; r < 4; ++r)
                out[(size_t)(r0 + r)*DIM + col] = acc[mi][ni][r] + bias;
        }
    }
}

// ---------------- attention v11 (measured best, 61us):
// 64 q-rows/wave, wave-pair s-split inside block, XCD-bijective swizzle
// (FETCH 70->8.7MB verified), 4-buf ring, vmcnt(8), ones-MFMA denominator.
__global__ __launch_bounds__(256, 2) void attn_kernel(
    const u16* __restrict__ q16, const u16* __restrict__ vt16,
    const float* __restrict__ qsq, const float* __restrict__ asq,
    const u32* __restrict__ bmaxsq, u16* __restrict__ ao16)
{
    const int tid = threadIdx.x;
    const int lane = tid & 63, w = tid >> 6;          // 4 waves
    const int l31 = lane & 31, hf = lane >> 5;
    const int l7 = lane & 7;
    const int ws = w & 1;                             // s-parity within pair
    const int p  = w >> 1;                            // q-pair (rows p*64..)
    const int bid = blockIdx.x;
    const int bh = (bid & 7) * 4 + (bid >> 7);        // XCD-grouped bh
    const int qtile = (bid >> 3) & 15;
    const int b = bh >> 3, head = bh & 7;

    // smem carve: 4 K bufs (32KB) | 4 V bufs (32KB) | cq (8KB)  = 72KB
    __shared__ __align__(16) u16 smem[36864];
    u16* ksA = smem;                 // [4][64*64] swizzled K [s][d]
    u16* vtA = smem + 16384;         // [4][64*64] swizzled V^T [d][s]
    float* cq = (float*)(smem + 32768);   // cf * qsq[s], s in [0,2048)

    const u16* qgp = q16  + (size_t)bh * TT * HD;     // [t][d]
    const u16* vgp = vt16 + (size_t)bh * HD * TT;     // [d][t]
    const float* qsqg = qsq + (size_t)bh * TT;

    float cf;   // 100 * log2(e) / (a * bmax + eps)
    {
        float a  = sqrtf(asq[bh]);
        float bm = sqrtf(__uint_as_float(bmaxsq[b]));
        cf = (100.0f * 1.44269504089f) / (a * bm + 1e-10f);
    }
    const float c2 = 2.0f * cf;

    // Q B-frags for 2 row-groups: lane holds Q[t=qt0+qg*32+l31][kc*16+hf*8+i]
    const int qt0 = qtile * 128 + p * 64;
    bf16x8 qf[2][4];
    #pragma unroll
    for (int qg = 0; qg < 2; ++qg) {
        const u16* qrow = qgp + (size_t)(qt0 + qg*32 + l31) * HD + hf * 8;
        #pragma unroll
        for (int kc = 0; kc < 4; ++kc)
            qf[qg][kc] = *(const bf16x8*)(qrow + kc * 16);
    }

    // cq staging regs (8 floats per thread)
    const int ci = tid * 8;
    f32x4 cqa = *(const f32x4*)(qsqg + ci);
    f32x4 cqb = *(const f32x4*)(qsqg + ci + 4);

    // swizzled slot offsets (elements): slot kc = ((2*kc + hf) ^ l7)*8
    int slot[4];
    #pragma unroll
    for (int kc = 0; kc < 4; ++kc) slot[kc] = (((2*kc + hf) ^ l7) << 3);

    // staging addresses (inverse-swizzled global source, linear LDS dest)
    const int rk = tid >> 3;
    const int ck = (tid & 7) ^ (rk & 7);
    const u16* kstg = qgp + (size_t)rk * HD + ck * 8;  // + t*64*HD per tile
    const u16* vstg = vgp + (size_t)rk * TT + ck * 8;  // + t*64 per tile
    const int lb0 = w * 512;                           // wave-uniform LDS base
    const int lb1 = 2048 + w * 512;

    // stage a PAIR of tiles {t0g, t0g+1} into ring slots {sb, sb+1}
    auto stagePair = [&](int sb, int t0g) {
        #pragma unroll
        for (int ts = 0; ts < 2; ++ts) {
            const u16* kp = kstg + (size_t)(t0g + ts) * 64 * HD;
            const u16* vp = vstg + (t0g + ts) * 64;
            u16* kb = ksA + (sb + ts) * 4096;
            u16* vb = vtA + (sb + ts) * 4096;
            gll16(kp,                 kb + lb0);
            gll16(kp + 32 * HD,       kb + lb1);
            gll16(vp,                 vb + lb0);
            gll16(vp + (size_t)32*TT, vb + lb1);
        }
    };

    // ones B-frag for denominator MFMA
    bf16x8 onesf;
    {
        union { u16 a[8]; bf16x8 v; } o;
        #pragma unroll
        for (int i = 0; i < 8; ++i) o.a[i] = 0x3F80;
        onesf = o.v;
    }

    f32x16 oacc[2][2], osum[2];
    #pragma unroll
    for (int qg = 0; qg < 2; ++qg) {
        #pragma unroll
        for (int r = 0; r < 16; ++r) { oacc[qg][0][r] = 0.f; oacc[qg][1][r] = 0.f; osum[qg][r] = 0.f; }
    }

    auto tile_compute = [&](const u16* __restrict__ ksb,
                            const u16* __restrict__ vtb, int s0) {
        bf16x8 pa[2][4];
        #pragma unroll
        for (int sc = 0; sc < 2; ++sc) {
            const u16* kbase = ksb + sc * 2048 + l31 * 64;
            bf16x8 kf0 = *(const bf16x8*)(kbase + slot[0]);
            bf16x8 kf1 = *(const bf16x8*)(kbase + slot[1]);
            bf16x8 kf2 = *(const bf16x8*)(kbase + slot[2]);
            bf16x8 kf3 = *(const bf16x8*)(kbase + slot[3]);
            f32x4 cq4[4];
            #pragma unroll
            for (int g = 0; g < 4; ++g)
                cq4[g] = *(const f32x4*)&cq[s0 + sc*32 + g*8 + hf*4];
            #pragma unroll
            for (int qg = 0; qg < 2; ++qg) {
                f32x16 acc;
                #pragma unroll
                for (int r = 0; r < 16; ++r) acc[r] = 0.0f;
                __builtin_amdgcn_s_setprio(1);
                acc = __builtin_amdgcn_mfma_f32_32x32x16_bf16(kf0, qf[qg][0], acc, 0, 0, 0);
                acc = __builtin_amdgcn_mfma_f32_32x32x16_bf16(kf1, qf[qg][1], acc, 0, 0, 0);
                acc = __builtin_amdgcn_mfma_f32_32x32x16_bf16(kf2, qf[qg][2], acc, 0, 0, 0);
                acc = __builtin_amdgcn_mfma_f32_32x32x16_bf16(kf3, qf[qg][3], acc, 0, 0, 0);
                __builtin_amdgcn_s_setprio(0);
                float pv[16];
                #pragma unroll
                for (int g = 0; g < 4; ++g) {
                    pv[4*g+0] = __builtin_amdgcn_exp2f(fmaf(c2, acc[4*g+0], -cq4[g][0]));
                    pv[4*g+1] = __builtin_amdgcn_exp2f(fmaf(c2, acc[4*g+1], -cq4[g][1]));
                    pv[4*g+2] = __builtin_amdgcn_exp2f(fmaf(c2, acc[4*g+2], -cq4[g][2]));
                    pv[4*g+3] = __builtin_amdgcn_exp2f(fmaf(c2, acc[4*g+3], -cq4[g][3]));
                }
                #pragma unroll
                for (int kh = 0; kh < 2; ++kh) {
                    u32 A0 = cvtpk(pv[8*kh+0], pv[8*kh+1]);
                    u32 B0 = cvtpk(pv[8*kh+4], pv[8*kh+5]);
                    u32 A1 = cvtpk(pv[8*kh+2], pv[8*kh+3]);
                    u32 B1 = cvtpk(pv[8*kh+6], pv[8*kh+7]);
                    u32x2 r0 = __builtin_amdgcn_permlane32_swap(A0, B0, false, false);
                    u32x2 r1 = __builtin_amdgcn_permlane32_swap(A1, B1, false, false);
                    union { u32 u[4]; bf16x8 v; } pw;
                    pw.u[0] = r0.x; pw.u[1] = r1.x; pw.u[2] = r0.y; pw.u[3] = r1.y;
                    pa[qg][sc*2 + kh] = pw.v;
                }
            }
        }
        // PV + denominator: each V frag feeds 2 qg; ones-MFMA row-sums P
        #pragma unroll
        for (int kc = 0; kc < 4; ++kc) {
            bf16x8 vf0 = *(const bf16x8*)(vtb + (0*32 + l31) * 64 + slot[kc]);
            bf16x8 vf1 = *(const bf16x8*)(vtb + (1*32 + l31) * 64 + slot[kc]);
            __builtin_amdgcn_s_setprio(1);
            #pragma unroll
            for (int qg = 0; qg < 2; ++qg) {
                oacc[qg][0] = __builtin_amdgcn_mfma_f32_32x32x16_bf16(
                    pa[qg][kc], vf0, oacc[qg][0], 0, 0, 0);
                oacc[qg][1] = __builtin_amdgcn_mfma_f32_32x32x16_bf16(
                    pa[qg][kc], vf1, oacc[qg][1], 0, 0, 0);
                osum[qg] = __builtin_amdgcn_mfma_f32_32x32x16_bf16(
                    pa[qg][kc], onesf, osum[qg], 0, 0, 0);
            }
            __builtin_amdgcn_s_setprio(0);
        }
    };

    // prologue: stage pairs 0,1 (tiles 0..3); cq table
    stagePair(0, 0);
    stagePair(2, 2);
    *(f32x4*)&cq[ci]     = cqa * cf;
    *(f32x4*)&cq[ci + 4] = cqb * cf;
    asm volatile("s_waitcnt lgkmcnt(0)" ::: "memory");
    __builtin_amdgcn_s_barrier();

    // 16 pairs of tiles; wave computes tile 2m+ws of pair m
    #pragma unroll 2
    for (int m = 0; m < 15; ++m) {
        asm volatile("s_waitcnt vmcnt(8)" ::: "memory");
        __builtin_amdgcn_s_barrier();
        const int sb = (m & 1) * 2;
        tile_compute(ksA + (sb + ws) * 4096, vtA + (sb + ws) * 4096,
                     (2*m + ws) * 64);
        __builtin_amdgcn_s_barrier();
        if (m <= 13) stagePair(sb, 2*(m + 2));
    }
    asm volatile("s_waitcnt vmcnt(0)" ::: "memory");
    __builtin_amdgcn_s_barrier();
    tile_compute(ksA + (2 + ws) * 4096, vtA + (2 + ws) * 4096,
                 (30 + ws) * 64);
    __builtin_amdgcn_s_barrier();   // all reads done before combine overlay

    // flash combine across the s-split wave pair (overlay K/V ring)
    float* cmb = (float*)smem;      // per pair: 64 lanes x 96 f32 = 24KB
    float* myc = cmb + p * 6144 + lane * 96;
    if (ws == 1) {
        #pragma unroll
        for (int qg = 0; qg < 2; ++qg) {
            #pragma unroll
            for (int dh = 0; dh < 2; ++dh)
                #pragma unroll
                for (int v4 = 0; v4 < 4; ++v4)
                    *(f32x4*)(myc + (qg*2 + dh)*16 + v4*4) =
                        f32x4{oacc[qg][dh][v4*4+0], oacc[qg][dh][v4*4+1],
                              oacc[qg][dh][v4*4+2], oacc[qg][dh][v4*4+3]};
            #pragma unroll
            for (int v4 = 0; v4 < 4; ++v4)
                *(f32x4*)(myc + 64 + qg*16 + v4*4) =
                    f32x4{osum[qg][v4*4+0], osum[qg][v4*4+1],
                          osum[qg][v4*4+2], osum[qg][v4*4+3]};
        }
    }
    asm volatile("s_waitcnt lgkmcnt(0)" ::: "memory");
    __builtin_amdgcn_s_barrier();
    if (ws == 0) {
        #pragma unroll
        for (int qg = 0; qg < 2; ++qg) {
            #pragma unroll
            for (int dh = 0; dh < 2; ++dh)
                #pragma unroll
                for (int r = 0; r < 16; ++r)
                    oacc[qg][dh][r] += myc[(qg*2 + dh)*16 + r];
            #pragma unroll
            for (int r = 0; r < 16; ++r)
                osum[qg][r] += myc[64 + qg*16 + r];
        }
        // O rows: t = qt0 + qg*32 + (reg&3) + 8*(reg>>2) + 4*hf; col d = dh*32+l31
        #pragma unroll
        for (int qg = 0; qg < 2; ++qg) {
            float inv[16];
            #pragma unroll
            for (int r = 0; r < 16; ++r) inv[r] = 1.0f / osum[qg][r];
            #pragma unroll
            for (int dh = 0; dh < 2; ++dh)
                #pragma unroll
                for (int g = 0; g < 4; ++g)
                    #pragma unroll
                    for (int r0 = 0; r0 < 4; ++r0) {
                        int t = qt0 + qg*32 + g*8 + hf*4 + r0;
                        ao16[((size_t)(b*TT + t))*DIM + head*HD + dh*32 + l31] =
                            f2bf(oacc[qg][dh][g*4 + r0] * inv[g*4 + r0]);
                    }
        }
    }
}

extern "C" void kernel_launch(void* const* d_in, const int* in_sizes, int n_in,
                              void* d_out, int out_size, void* d_ws, size_t ws_size,
                              hipStream_t stream)
{
    const float* x     = (const float*)d_in[0];   // [4,2048,512] f32
    const float* Wqkv  = (const float*)d_in[1];   // [512,1024]  f32
    const float* Wproj = (const float*)d_in[2];   // [512,512]   f32
    const float* bproj = (const float*)d_in[3];   // [512]       f32
    float* out = (float*)d_out;                   // [4,2048,512] f32

    char* ws = (char*)d_ws;
    const size_t MB = 1024*1024;
    u16*   q16  = (u16*)(ws);                          // 8 MB  [b,h,t,d] bf16
    u16*   vt16 = (u16*)(ws + 8*MB);                   // 8 MB  [b,h,d,t] bf16
    u16*   ao16 = (u16*)(ws + 16*MB);                  // 8 MB  [b,t,dim] bf16
    u16*   x16  = (u16*)(ws + 24*MB);                  // 8 MB  [b,t,dim] bf16
    u16*   Wtq  = (u16*)(ws + 32*MB);                  // 1 MB  [1024][512]
    u16*   Wtp  = (u16*)(ws + 33*MB);                  // 0.5MB [512][512]
    float* qsq  = (float*)(ws + 34*MB);                // 256 KB (16B aligned)
    float* asq  = (float*)(ws + 34*MB + 262144);       // 128 B
    u32* bmaxsq = (u32*)(ws + 34*MB + 262144 + 128);   // 16 B

    (void)in_sizes; (void)n_in; (void)out_size; (void)ws_size;

    // zero qsq (atomically accumulated in qkv) + asq + bmaxsq
    hipMemsetAsync(ws + 34*MB, 0, 262144 + 144, stream);

    prep_kernel<<<1024, 256, 0, stream>>>(x, x16, bmaxsq, Wqkv, Wtq, Wproj, Wtp);

    qkv_mfma<<<64*8, 256, 0, stream>>>(x16, Wtq, q16, vt16, qsq, asq);

    attn_kernel<<<BH*16, 256, 0, stream>>>(q16, vt16, qsq, asq, bmaxsq, ao16);

    proj_mfma<<<64*8, 256, 0, stream>>>(ao16, Wtp, bproj, out);
}

// Round 12
// 111.379 us; speedup vs baseline: 1.5967x; 1.5967x over previous
//
#include <hip/hip_runtime.h>
#include <hip/hip_bf16.h>

#define BB 4
#define TT 2048
#define DIM 512
#define NH 8
#define HD 64
#define NROW (BB*TT)   // 8192
#define BH (BB*NH)     // 32

typedef unsigned short u16;
typedef unsigned int u32;
typedef __attribute__((ext_vector_type(8))) short bf16x8;   // 8 bf16 = 4 VGPRs
typedef __attribute__((ext_vector_type(8))) unsigned short u16x8;
typedef __attribute__((ext_vector_type(4))) float f32x4;
typedef __attribute__((ext_vector_type(16))) float f32x16;
typedef __attribute__((ext_vector_type(4))) unsigned short u16x4;
typedef __attribute__((ext_vector_type(2))) unsigned int u32x2;

static __device__ __forceinline__ float bf2f(u16 u) {
    return __uint_as_float(((u32)u) << 16);
}
static __device__ __forceinline__ u16 f2bf(float f) {
    u32 u = __float_as_uint(f);
    u32 r = (u + 0x7FFFu + ((u >> 16) & 1u)) >> 16;
    return (u16)r;
}
// packed f32x2 -> bf16x2 (v_cvt_pk_bf16_f32 on gfx950)
static __device__ __forceinline__ u32 cvtpk(float a, float b) {
    union { __hip_bfloat162 h2; u32 u; } cv;
    cv.h2 = __float22bfloat162_rn(make_float2(a, b));
    return cv.u;
}
// async global -> LDS, 16B per lane. LDS dest = wave-uniform base + lane*16.
static __device__ __forceinline__ void gll16(const u16* g, u16* l) {
    __builtin_amdgcn_global_load_lds(
        (const __attribute__((address_space(1))) unsigned int*)g,
        (__attribute__((address_space(3))) unsigned int*)l,
        16, 0, 0);
}

// ---------------- prep: fused convert_x (blocks 0..255) + W transposes
__global__ __launch_bounds__(256) void prep_kernel(
    const float* __restrict__ x, u16* __restrict__ x16, u32* __restrict__ bmaxsq,
    const float* __restrict__ Wqkv, u16* __restrict__ Wtq,
    const float* __restrict__ Wproj, u16* __restrict__ Wtp)
{
    const int bid = blockIdx.x;
    const int tid = threadIdx.x;
    __shared__ u16 t[32][33];
    __shared__ float red[4];

    if (bid < 256) {
        const int row = bid * 32 + (tid >> 3);
        const int b = (bid * 32) >> 11;
        const float* xr = x   + (size_t)row * DIM + (tid & 7) * 64;
        u16*        xo  = x16 + (size_t)row * DIM + (tid & 7) * 64;
        float s = 0.0f;
        #pragma unroll
        for (int j = 0; j < 8; ++j) {
            float4 a = *(const float4*)(xr + j*8);
            float4 c = *(const float4*)(xr + j*8 + 4);
            s += a.x*a.x + a.y*a.y + a.z*a.z + a.w*a.w;
            s += c.x*c.x + c.y*c.y + c.z*c.z + c.w*c.w;
            u16x8 pk;
            pk[0]=f2bf(a.x); pk[1]=f2bf(a.y); pk[2]=f2bf(a.z); pk[3]=f2bf(a.w);
            pk[4]=f2bf(c.x); pk[5]=f2bf(c.y); pk[6]=f2bf(c.z); pk[7]=f2bf(c.w);
            *(u16x8*)(xo + j*8) = pk;
        }
        #pragma unroll
        for (int off = 1; off < 8; off <<= 1) s += __shfl_xor(s, off, 64);
        float m = s;
        #pragma unroll
        for (int off = 8; off < 64; off <<= 1) m = fmaxf(m, __shfl_xor(m, off, 64));
        if ((tid & 63) == 0) red[tid >> 6] = m;
        __syncthreads();
        if (tid == 0) {
            float mx = fmaxf(fmaxf(red[0], red[1]), fmaxf(red[2], red[3]));
            atomicMax(&bmaxsq[b], __float_as_uint(mx));
        }
    } else {
        const float* in; u16* outp; int K, N, tb;
        if (bid < 768) { in = Wqkv; outp = Wtq; K = 512; N = 1024; tb = bid - 256; }
        else           { in = Wproj; outp = Wtp; K = 512; N = 512;  tb = bid - 768; }
        const int ntiles = N >> 5;
        const int bx = tb % ntiles, by = tb / ntiles;
        const int n0 = bx * 32, k0 = by * 32;
        const int tx = tid & 31, ty = tid >> 5;
        #pragma unroll
        for (int i = 0; i < 32; i += 8)
            t[ty + i][tx] = f2bf(in[(size_t)(k0 + ty + i) * N + n0 + tx]);
        __syncthreads();
        #pragma unroll
        for (int i = 0; i < 32; i += 8)
            outp[(size_t)(n0 + ty + i) * K + k0 + tx] = t[tx][ty + i];
    }
}

// ---------------- MFMA GEMM: qkv = x16 @ Wqkv (via Wt [1024][512] bf16)
// v4: dbuf gll16 staging (vmcnt(8)) + LDS-transposed COALESCED epilogue.
__global__ __launch_bounds__(256) void qkv_mfma(
    const u16* __restrict__ x16, const u16* __restrict__ Wt,
    u16* __restrict__ q16, u16* __restrict__ vt16)
{
    const int tid = threadIdx.x, lane = tid & 63, w = tid >> 6;
    const int li = lane & 15, quad = lane >> 4;
    const int mb = blockIdx.x >> 3, nb = blockIdx.x & 7;   // 64 x 8
    const int row0 = mb * 128, n0 = nb * 128;
    const int b = row0 >> 11;
    const int wm = w >> 1, wn = w & 1;

    __shared__ __align__(16) u16 smemq[32768];   // 64KB: staging + epilogue
    u16* as0 = smemq;            // [2][8192] A bufs
    u16* bs0 = smemq + 16384;    // [2][8192] B bufs

    const int rstg = tid >> 3;
    const int cstg = ((tid & 7) ^ (rstg & 7)) * 8;
    const u16* xa = x16 + (size_t)(row0 + rstg) * DIM + cstg;
    const u16* wb = Wt  + (size_t)(n0  + rstg) * DIM + cstg;
    const int ldb = w * 512;                               // wave-uniform base

    const int fs0 = ((quad)     ^ (li & 7)) << 3;
    const int fs1 = ((quad + 4) ^ (li & 7)) << 3;

    auto stage = [&](int bf, int k0) {
        #pragma unroll
        for (int it = 0; it < 4; ++it) {
            gll16(xa + k0 + (size_t)it * 32 * DIM, as0 + bf*8192 + it*2048 + ldb);
            gll16(wb + k0 + (size_t)it * 32 * DIM, bs0 + bf*8192 + it*2048 + ldb);
        }
    };

    f32x4 acc[4][4];
    #pragma unroll
    for (int mi = 0; mi < 4; ++mi)
        #pragma unroll
        for (int ni = 0; ni < 4; ++ni) acc[mi][ni] = f32x4{0.f,0.f,0.f,0.f};

    stage(0, 0);
    for (int ki = 0; ki < 8; ++ki) {
        const int cur = ki & 1;
        if (ki < 7) {
            stage(cur ^ 1, (ki + 1) * 64);
            asm volatile("s_waitcnt vmcnt(8)" ::: "memory");
        } else {
            asm volatile("s_waitcnt vmcnt(0)" ::: "memory");
        }
        __syncthreads();

        bf16x8 af[4][2], bfr[4][2];
        #pragma unroll
        for (int mi = 0; mi < 4; ++mi) {
            const u16* p = &as0[cur*8192 + (wm*64 + mi*16 + li) * 64];
            af[mi][0] = *(const bf16x8*)(p + fs0);
            af[mi][1] = *(const bf16x8*)(p + fs1);
        }
        #pragma unroll
        for (int ni = 0; ni < 4; ++ni) {
            const u16* p = &bs0[cur*8192 + (wn*64 + ni*16 + li) * 64];
            bfr[ni][0] = *(const bf16x8*)(p + fs0);
            bfr[ni][1] = *(const bf16x8*)(p + fs1);
        }
        #pragma unroll
        for (int mi = 0; mi < 4; ++mi)
            #pragma unroll
            for (int ni = 0; ni < 4; ++ni) {
                acc[mi][ni] = __builtin_amdgcn_mfma_f32_16x16x32_bf16(
                    af[mi][0], bfr[ni][0], acc[mi][ni], 0, 0, 0);
                acc[mi][ni] = __builtin_amdgcn_mfma_f32_16x16x32_bf16(
                    af[mi][1], bfr[ni][1], acc[mi][ni], 0, 0, 0);
            }
        __syncthreads();
    }

    // ---- epilogue: acc -> LDS [c_local 128][t 128] bf16 (stride 132) ----
    u16* eps = smemq;   // 128*132*2 = 33792 B, staging fully consumed
    const int cbase = wn*64 + li;
    const int tbase = wm*64 + quad*4;
    #pragma unroll
    for (int ni = 0; ni < 4; ++ni)
        #pragma unroll
        for (int mi = 0; mi < 4; ++mi) {
            union { u32 u[2]; u16x4 v; } pk;
            pk.u[0] = cvtpk(acc[mi][ni][0], acc[mi][ni][1]);
            pk.u[1] = cvtpk(acc[mi][ni][2], acc[mi][ni][3]);
            *(u16x4*)&eps[(cbase + ni*16)*132 + tbase + mi*16] = pk.v;
        }
    __syncthreads();

    const int trow = row0 & (TT-1);
    const int d0 = n0 >> 4;
    // q: c_local = dl*16 + h (k=0). Chunk (h,t): gather 8 u16 -> 16B store.
    #pragma unroll
    for (int it = 0; it < 4; ++it) {
        int id = it*256 + tid;
        int h = id >> 7, t = id & 127;
        union { u16 a[8]; u16x8 v; } ch;
        #pragma unroll
        for (int dl = 0; dl < 8; ++dl)
            ch.a[dl] = eps[(dl*16 + h)*132 + t];
        *(u16x8*)(q16 + ((size_t)(b*NH + h)*TT + trow + t)*HD + d0) = ch.v;
    }
    // v: c_local = dl*16 + 8 + h (k=1). Row-contig LDS -> coalesced 16B.
    #pragma unroll
    for (int it = 0; it < 4; ++it) {
        int id = it*256 + tid;
        int tc = id & 15, dl = (id >> 4) & 7, h = id >> 7;
        union { u16x4 a[2]; u16x8 v; } ch;
        ch.a[0] = *(const u16x4*)&eps[(dl*16 + 8 + h)*132 + tc*8];
        ch.a[1] = *(const u16x4*)&eps[(dl*16 + 8 + h)*132 + tc*8 + 4];
        *(u16x8*)(vt16 + ((size_t)(b*NH + h)*HD + d0 + dl)*TT + trow + tc*8) = ch.v;
    }
}

// ---------------- MFMA GEMM: out(f32) = ao16 @ Wproj + bias(f32)
// v3: N-tile 64 (grid 512 -> 2 blocks/CU), dbuf gll16 staging, vmcnt(6).
__global__ __launch_bounds__(256) void proj_mfma(
    const u16* __restrict__ ao16, const u16* __restrict__ Wt,
    const float* __restrict__ bp, float* __restrict__ out)
{
    const int tid = threadIdx.x, lane = tid & 63, w = tid >> 6;
    const int li = lane & 15, quad = lane >> 4;
    const int mb = blockIdx.x >> 3, nb = blockIdx.x & 7;   // 64 x 8
    const int row0 = mb * 128, n0 = nb * 64;
    const int wm = w >> 1, wn = w & 1;

    __shared__ __align__(16) u16 as[2][128 * 64];
    __shared__ __align__(16) u16 bs[2][64 * 64];

    const int rstg = tid >> 3;
    const int cstg = ((tid & 7) ^ (rstg & 7)) * 8;
    const u16* xa = ao16 + (size_t)(row0 + rstg) * DIM + cstg;
    const u16* wb = Wt   + (size_t)(n0  + rstg) * DIM + cstg;
    const int ldb = w * 512;

    const int fs0 = ((quad)     ^ (li & 7)) << 3;
    const int fs1 = ((quad + 4) ^ (li & 7)) << 3;

    auto stage = [&](int bf, int k0) {
        #pragma unroll
        for (int it = 0; it < 4; ++it)
            gll16(xa + k0 + (size_t)it * 32 * DIM, &as[bf][0] + it * 2048 + ldb);
        #pragma unroll
        for (int it = 0; it < 2; ++it)
            gll16(wb + k0 + (size_t)it * 32 * DIM, &bs[bf][0] + it * 2048 + ldb);
    };

    f32x4 acc[4][2];
    #pragma unroll
    for (int mi = 0; mi < 4; ++mi)
        #pragma unroll
        for (int ni = 0; ni < 2; ++ni) acc[mi][ni] = f32x4{0.f,0.f,0.f,0.f};

    stage(0, 0);
    for (int ki = 0; ki < 8; ++ki) {
        const int cur = ki & 1;
        if (ki < 7) {
            stage(cur ^ 1, (ki + 1) * 64);
            asm volatile("s_waitcnt vmcnt(6)" ::: "memory");
        } else {
            asm volatile("s_waitcnt vmcnt(0)" ::: "memory");
        }
        __syncthreads();

        bf16x8 af[4][2], bfr[2][2];
        #pragma unroll
        for (int mi = 0; mi < 4; ++mi) {
            const u16* p = &as[cur][(wm*64 + mi*16 + li) * 64];
            af[mi][0] = *(const bf16x8*)(p + fs0);
            af[mi][1] = *(const bf16x8*)(p + fs1);
        }
        #pragma unroll
        for (int ni = 0; ni < 2; ++ni) {
            const u16* p = &bs[cur][(wn*32 + ni*16 + li) * 64];
            bfr[ni][0] = *(const bf16x8*)(p + fs0);
            bfr[ni][1] = *(const bf16x8*)(p + fs1);
        }
        #pragma unroll
        for (int mi = 0; mi < 4; ++mi)
            #pragma unroll
            for (int ni = 0; ni < 2; ++ni) {
                acc[mi][ni] = __builtin_amdgcn_mfma_f32_16x16x32_bf16(
                    af[mi][0], bfr[ni][0], acc[mi][ni], 0, 0, 0);
                acc[mi][ni] = __builtin_amdgcn_mfma_f32_16x16x32_bf16(
                    af[mi][1], bfr[ni][1], acc[mi][ni], 0, 0, 0);
            }
        __syncthreads();
    }

    #pragma unroll
    for (int ni = 0; ni < 2; ++ni) {
        int col = n0 + wn*32 + ni*16 + li;
        float bias = bp[col];
        #pragma unroll
        for (int mi = 0; mi < 4; ++mi) {
            int r0 = row0 + wm*64 + mi*16 + quad*4;
            #pragma unroll
            for (int r = 0; r < 4; ++r)
                out[(size_t)(r0 + r)*DIM + col] = acc[mi][ni][r] + bias;
        }
    }
}

// ---------------- qsq: qsq[b,h,t] = sum_d q^2 ; asq[b,h] via 1 atomic/block
__global__ __launch_bounds__(256) void qsq_kernel(
    const u16* __restrict__ q16, float* __restrict__ qsq, float* __restrict__ asq)
{
    const int tid = threadIdx.x;
    const int bh = blockIdx.x >> 3;
    const int r0 = (blockIdx.x & 7) * 256;
    const u16* qb = q16 + ((size_t)bh * TT + r0) * HD;

    float tot = 0.0f;
    #pragma unroll
    for (int i = 0; i < 8; ++i) {
        int row = i * 32 + (tid >> 3);
        u16x8 v = *(const u16x8*)(qb + (size_t)row * HD + (tid & 7) * 8);
        float s = 0.0f;
        #pragma unroll
        for (int j = 0; j < 8; ++j) { float f = bf2f(v[j]); s += f * f; }
        tot += s;
        #pragma unroll
        for (int off = 1; off < 8; off <<= 1) s += __shfl_xor(s, off, 64);
        if ((tid & 7) == 0) qsq[(size_t)bh * TT + r0 + row] = s;
    }
    __shared__ float red[4];
    #pragma unroll
    for (int off = 32; off > 0; off >>= 1) tot += __shfl_down(tot, off, 64);
    if ((tid & 63) == 0) red[tid >> 6] = tot;
    __syncthreads();
    if (tid == 0) atomicAdd(&asq[bh], red[0] + red[1] + red[2] + red[3]);
}

// ---------------- attention v11 (measured best, 61us):
// 64 q-rows/wave, wave-pair s-split inside block, XCD-bijective swizzle
// (FETCH 70->8.7MB verified), 4-buf ring, vmcnt(8), ones-MFMA denominator.
__global__ __launch_bounds__(256, 2) void attn_kernel(
    const u16* __restrict__ q16, const u16* __restrict__ vt16,
    const float* __restrict__ qsq, const float* __restrict__ asq,
    const u32* __restrict__ bmaxsq, u16* __restrict__ ao16)
{
    const int tid = threadIdx.x;
    const int lane = tid & 63, w = tid >> 6;          // 4 waves
    const int l31 = lane & 31, hf = lane >> 5;
    const int l7 = lane & 7;
    const int ws = w & 1;                             // s-parity within pair
    const int p  = w >> 1;                            // q-pair (rows p*64..)
    const int bid = blockIdx.x;
    const int bh = (bid & 7) * 4 + (bid >> 7);        // XCD-grouped bh
    const int qtile = (bid >> 3) & 15;
    const int b = bh >> 3, head = bh & 7;

    // smem carve: 4 K bufs (32KB) | 4 V bufs (32KB) | cq (8KB)  = 72KB
    __shared__ __align__(16) u16 smem[36864];
    u16* ksA = smem;                 // [4][64*64] swizzled K [s][d]
    u16* vtA = smem + 16384;         // [4][64*64] swizzled V^T [d][s]
    float* cq = (float*)(smem + 32768);   // cf * qsq[s], s in [0,2048)

    const u16* qgp = q16  + (size_t)bh * TT * HD;     // [t][d]
    const u16* vgp = vt16 + (size_t)bh * HD * TT;     // [d][t]
    const float* qsqg = qsq + (size_t)bh * TT;

    float cf;   // 100 * log2(e) / (a * bmax + eps)
    {
        float a  = sqrtf(asq[bh]);
        float bm = sqrtf(__uint_as_float(bmaxsq[b]));
        cf = (100.0f * 1.44269504089f) / (a * bm + 1e-10f);
    }
    const float c2 = 2.0f * cf;

    // Q B-frags for 2 row-groups: lane holds Q[t=qt0+qg*32+l31][kc*16+hf*8+i]
    const int qt0 = qtile * 128 + p * 64;
    bf16x8 qf[2][4];
    #pragma unroll
    for (int qg = 0; qg < 2; ++qg) {
        const u16* qrow = qgp + (size_t)(qt0 + qg*32 + l31) * HD + hf * 8;
        #pragma unroll
        for (int kc = 0; kc < 4; ++kc)
            qf[qg][kc] = *(const bf16x8*)(qrow + kc * 16);
    }

    // cq staging regs (8 floats per thread)
    const int ci = tid * 8;
    f32x4 cqa = *(const f32x4*)(qsqg + ci);
    f32x4 cqb = *(const f32x4*)(qsqg + ci + 4);

    // swizzled slot offsets (elements): slot kc = ((2*kc + hf) ^ l7)*8
    int slot[4];
    #pragma unroll
    for (int kc = 0; kc < 4; ++kc) slot[kc] = (((2*kc + hf) ^ l7) << 3);

    // staging addresses (inverse-swizzled global source, linear LDS dest)
    const int rk = tid >> 3;
    const int ck = (tid & 7) ^ (rk & 7);
    const u16* kstg = qgp + (size_t)rk * HD + ck * 8;  // + t*64*HD per tile
    const u16* vstg = vgp + (size_t)rk * TT + ck * 8;  // + t*64 per tile
    const int lb0 = w * 512;                           // wave-uniform LDS base
    const int lb1 = 2048 + w * 512;

    // stage a PAIR of tiles {t0g, t0g+1} into ring slots {sb, sb+1}
    auto stagePair = [&](int sb, int t0g) {
        #pragma unroll
        for (int ts = 0; ts < 2; ++ts) {
            const u16* kp = kstg + (size_t)(t0g + ts) * 64 * HD;
            const u16* vp = vstg + (t0g + ts) * 64;
            u16* kb = ksA + (sb + ts) * 4096;
            u16* vb = vtA + (sb + ts) * 4096;
            gll16(kp,                 kb + lb0);
            gll16(kp + 32 * HD,       kb + lb1);
            gll16(vp,                 vb + lb0);
            gll16(vp + (size_t)32*TT, vb + lb1);
        }
    };

    // ones B-frag for denominator MFMA
    bf16x8 onesf;
    {
        union { u16 a[8]; bf16x8 v; } o;
        #pragma unroll
        for (int i = 0; i < 8; ++i) o.a[i] = 0x3F80;
        onesf = o.v;
    }

    f32x16 oacc[2][2], osum[2];
    #pragma unroll
    for (int qg = 0; qg < 2; ++qg) {
        #pragma unroll
        for (int r = 0; r < 16; ++r) { oacc[qg][0][r] = 0.f; oacc[qg][1][r] = 0.f; osum[qg][r] = 0.f; }
    }

    auto tile_compute = [&](const u16* __restrict__ ksb,
                            const u16* __restrict__ vtb, int s0) {
        bf16x8 pa[2][4];
        #pragma unroll
        for (int sc = 0; sc < 2; ++sc) {
            const u16* kbase = ksb + sc * 2048 + l31 * 64;
            bf16x8 kf0 = *(const bf16x8*)(kbase + slot[0]);
            bf16x8 kf1 = *(const bf16x8*)(kbase + slot[1]);
            bf16x8 kf2 = *(const bf16x8*)(kbase + slot[2]);
            bf16x8 kf3 = *(const bf16x8*)(kbase + slot[3]);
            f32x4 cq4[4];
            #pragma unroll
            for (int g = 0; g < 4; ++g)
                cq4[g] = *(const f32x4*)&cq[s0 + sc*32 + g*8 + hf*4];
            #pragma unroll
            for (int qg = 0; qg < 2; ++qg) {
                f32x16 acc;
                #pragma unroll
                for (int r = 0; r < 16; ++r) acc[r] = 0.0f;
                __builtin_amdgcn_s_setprio(1);
                acc = __builtin_amdgcn_mfma_f32_32x32x16_bf16(kf0, qf[qg][0], acc, 0, 0, 0);
                acc = __builtin_amdgcn_mfma_f32_32x32x16_bf16(kf1, qf[qg][1], acc, 0, 0, 0);
                acc = __builtin_amdgcn_mfma_f32_32x32x16_bf16(kf2, qf[qg][2], acc, 0, 0, 0);
                acc = __builtin_amdgcn_mfma_f32_32x32x16_bf16(kf3, qf[qg][3], acc, 0, 0, 0);
                __builtin_amdgcn_s_setprio(0);
                float pv[16];
                #pragma unroll
                for (int g = 0; g < 4; ++g) {
                    pv[4*g+0] = __builtin_amdgcn_exp2f(fmaf(c2, acc[4*g+0], -cq4[g][0]));
                    pv[4*g+1] = __builtin_amdgcn_exp2f(fmaf(c2, acc[4*g+1], -cq4[g][1]));
                    pv[4*g+2] = __builtin_amdgcn_exp2f(fmaf(c2, acc[4*g+2], -cq4[g][2]));
                    pv[4*g+3] = __builtin_amdgcn_exp2f(fmaf(c2, acc[4*g+3], -cq4[g][3]));
                }
                #pragma unroll
                for (int kh = 0; kh < 2; ++kh) {
                    u32 A0 = cvtpk(pv[8*kh+0], pv[8*kh+1]);
                    u32 B0 = cvtpk(pv[8*kh+4], pv[8*kh+5]);
                    u32 A1 = cvtpk(pv[8*kh+2], pv[8*kh+3]);
                    u32 B1 = cvtpk(pv[8*kh+6], pv[8*kh+7]);
                    u32x2 r0 = __builtin_amdgcn_permlane32_swap(A0, B0, false, false);
                    u32x2 r1 = __builtin_amdgcn_permlane32_swap(A1, B1, false, false);
                    union { u32 u[4]; bf16x8 v; } pw;
                    pw.u[0] = r0.x; pw.u[1] = r1.x; pw.u[2] = r0.y; pw.u[3] = r1.y;
                    pa[qg][sc*2 + kh] = pw.v;
                }
            }
        }
        // PV + denominator: each V frag feeds 2 qg; ones-MFMA row-sums P
        #pragma unroll
        for (int kc = 0; kc < 4; ++kc) {
            bf16x8 vf0 = *(const bf16x8*)(vtb + (0*32 + l31) * 64 + slot[kc]);
            bf16x8 vf1 = *(const bf16x8*)(vtb + (1*32 + l31) * 64 + slot[kc]);
            __builtin_amdgcn_s_setprio(1);
            #pragma unroll
            for (int qg = 0; qg < 2; ++qg) {
                oacc[qg][0] = __builtin_amdgcn_mfma_f32_32x32x16_bf16(
                    pa[qg][kc], vf0, oacc[qg][0], 0, 0, 0);
                oacc[qg][1] = __builtin_amdgcn_mfma_f32_32x32x16_bf16(
                    pa[qg][kc], vf1, oacc[qg][1], 0, 0, 0);
                osum[qg] = __builtin_amdgcn_mfma_f32_32x32x16_bf16(
                    pa[qg][kc], onesf, osum[qg], 0, 0, 0);
            }
            __builtin_amdgcn_s_setprio(0);
        }
    };

    // prologue: stage pairs 0,1 (tiles 0..3); cq table
    stagePair(0, 0);
    stagePair(2, 2);
    *(f32x4*)&cq[ci]     = cqa * cf;
    *(f32x4*)&cq[ci + 4] = cqb * cf;
    asm volatile("s_waitcnt lgkmcnt(0)" ::: "memory");
    __builtin_amdgcn_s_barrier();

    // 16 pairs of tiles; wave computes tile 2m+ws of pair m
    #pragma unroll 2
    for (int m = 0; m < 15; ++m) {
        asm volatile("s_waitcnt vmcnt(8)" ::: "memory");
        __builtin_amdgcn_s_barrier();
        const int sb = (m & 1) * 2;
        tile_compute(ksA + (sb + ws) * 4096, vtA + (sb + ws) * 4096,
                     (2*m + ws) * 64);
        __builtin_amdgcn_s_barrier();
        if (m <= 13) stagePair(sb, 2*(m + 2));
    }
    asm volatile("s_waitcnt vmcnt(0)" ::: "memory");
    __builtin_amdgcn_s_barrier();
    tile_compute(ksA + (2 + ws) * 4096, vtA + (2 + ws) * 4096,
                 (30 + ws) * 64);
    __builtin_amdgcn_s_barrier();   // all reads done before combine overlay

    // flash combine across the s-split wave pair (overlay K/V ring)
    float* cmb = (float*)smem;      // per pair: 64 lanes x 96 f32 = 24KB
    float* myc = cmb + p * 6144 + lane * 96;
    if (ws == 1) {
        #pragma unroll
        for (int qg = 0; qg < 2; ++qg) {
            #pragma unroll
            for (int dh = 0; dh < 2; ++dh)
                #pragma unroll
                for (int v4 = 0; v4 < 4; ++v4)
                    *(f32x4*)(myc + (qg*2 + dh)*16 + v4*4) =
                        f32x4{oacc[qg][dh][v4*4+0], oacc[qg][dh][v4*4+1],
                              oacc[qg][dh][v4*4+2], oacc[qg][dh][v4*4+3]};
            #pragma unroll
            for (int v4 = 0; v4 < 4; ++v4)
                *(f32x4*)(myc + 64 + qg*16 + v4*4) =
                    f32x4{osum[qg][v4*4+0], osum[qg][v4*4+1],
                          osum[qg][v4*4+2], osum[qg][v4*4+3]};
        }
    }
    asm volatile("s_waitcnt lgkmcnt(0)" ::: "memory");
    __builtin_amdgcn_s_barrier();
    if (ws == 0) {
        #pragma unroll
        for (int qg = 0; qg < 2; ++qg) {
            #pragma unroll
            for (int dh = 0; dh < 2; ++dh)
                #pragma unroll
                for (int r = 0; r < 16; ++r)
                    oacc[qg][dh][r] += myc[(qg*2 + dh)*16 + r];
            #pragma unroll
            for (int r = 0; r < 16; ++r)
                osum[qg][r] += myc[64 + qg*16 + r];
        }
        // O rows: t = qt0 + qg*32 + (reg&3) + 8*(reg>>2) + 4*hf; col d = dh*32+l31
        #pragma unroll
        for (int qg = 0; qg < 2; ++qg) {
            float inv[16];
            #pragma unroll
            for (int r = 0; r < 16; ++r) inv[r] = 1.0f / osum[qg][r];
            #pragma unroll
            for (int dh = 0; dh < 2; ++dh)
                #pragma unroll
                for (int g = 0; g < 4; ++g)
                    #pragma unroll
                    for (int r0 = 0; r0 < 4; ++r0) {
                        int t = qt0 + qg*32 + g*8 + hf*4 + r0;
                        ao16[((size_t)(b*TT + t))*DIM + head*HD + dh*32 + l31] =
                            f2bf(oacc[qg][dh][g*4 + r0] * inv[g*4 + r0]);
                    }
        }
    }
}

extern "C" void kernel_launch(void* const* d_in, const int* in_sizes, int n_in,
                              void* d_out, int out_size, void* d_ws, size_t ws_size,
                              hipStream_t stream)
{
    const float* x     = (const float*)d_in[0];   // [4,2048,512] f32
    const float* Wqkv  = (const float*)d_in[1];   // [512,1024]  f32
    const float* Wproj = (const float*)d_in[2];   // [512,512]   f32
    const float* bproj = (const float*)d_in[3];   // [512]       f32
    float* out = (float*)d_out;                   // [4,2048,512] f32

    char* ws = (char*)d_ws;
    const size_t MB = 1024*1024;
    u16*   q16  = (u16*)(ws);                          // 8 MB  [b,h,t,d] bf16
    u16*   vt16 = (u16*)(ws + 8*MB);                   // 8 MB  [b,h,d,t] bf16
    u16*   ao16 = (u16*)(ws + 16*MB);                  // 8 MB  [b,t,dim] bf16
    u16*   x16  = (u16*)(ws + 24*MB);                  // 8 MB  [b,t,dim] bf16
    u16*   Wtq  = (u16*)(ws + 32*MB);                  // 1 MB  [1024][512]
    u16*   Wtp  = (u16*)(ws + 33*MB);                  // 0.5MB [512][512]
    float* qsq  = (float*)(ws + 34*MB);                // 256 KB (16B aligned)
    float* asq  = (float*)(ws + 34*MB + 262144);       // 128 B
    u32* bmaxsq = (u32*)(ws + 34*MB + 262144 + 128);   // 16 B

    (void)in_sizes; (void)n_in; (void)out_size; (void)ws_size;

    hipMemsetAsync(ws + 34*MB + 262144, 0, 144, stream);

    prep_kernel<<<1024, 256, 0, stream>>>(x, x16, bmaxsq, Wqkv, Wtq, Wproj, Wtp);

    qkv_mfma<<<64*8, 256, 0, stream>>>(x16, Wtq, q16, vt16);

    qsq_kernel<<<BH*8, 256, 0, stream>>>(q16, qsq, asq);

    attn_kernel<<<BH*16, 256, 0, stream>>>(q16, vt16, qsq, asq, bmaxsq, ao16);

    proj_mfma<<<64*8, 256, 0, stream>>>(ao16, Wtp, bproj, out);
}

// Round 13
// 109.183 us; speedup vs baseline: 1.6288x; 1.0201x over previous
//
#include <hip/hip_runtime.h>
#include <hip/hip_bf16.h>

#define BB 4
#define TT 2048
#define DIM 512
#define NH 8
#define HD 64
#define NROW (BB*TT)   // 8192
#define BH (BB*NH)     // 32

typedef unsigned short u16;
typedef unsigned int u32;
typedef __attribute__((ext_vector_type(8))) short bf16x8;   // 8 bf16 = 4 VGPRs
typedef __attribute__((ext_vector_type(8))) unsigned short u16x8;
typedef __attribute__((ext_vector_type(4))) float f32x4;
typedef __attribute__((ext_vector_type(16))) float f32x16;
typedef __attribute__((ext_vector_type(4))) unsigned short u16x4;
typedef __attribute__((ext_vector_type(2))) unsigned int u32x2;

static __device__ __forceinline__ float bf2f(u16 u) {
    return __uint_as_float(((u32)u) << 16);
}
static __device__ __forceinline__ u16 f2bf(float f) {
    u32 u = __float_as_uint(f);
    u32 r = (u + 0x7FFFu + ((u >> 16) & 1u)) >> 16;
    return (u16)r;
}
// packed f32x2 -> bf16x2 (v_cvt_pk_bf16_f32 on gfx950)
static __device__ __forceinline__ u32 cvtpk(float a, float b) {
    union { __hip_bfloat162 h2; u32 u; } cv;
    cv.h2 = __float22bfloat162_rn(make_float2(a, b));
    return cv.u;
}
// async global -> LDS, 16B per lane. LDS dest = wave-uniform base + lane*16.
static __device__ __forceinline__ void gll16(const u16* g, u16* l) {
    __builtin_amdgcn_global_load_lds(
        (const __attribute__((address_space(1))) unsigned int*)g,
        (__attribute__((address_space(3))) unsigned int*)l,
        16, 0, 0);
}

// ---------------- prep: fused convert_x (blocks 0..255) + W transposes
__global__ __launch_bounds__(256) void prep_kernel(
    const float* __restrict__ x, u16* __restrict__ x16, u32* __restrict__ bmaxsq,
    const float* __restrict__ Wqkv, u16* __restrict__ Wtq,
    const float* __restrict__ Wproj, u16* __restrict__ Wtp)
{
    const int bid = blockIdx.x;
    const int tid = threadIdx.x;
    __shared__ u16 t[32][33];
    __shared__ float red[4];

    if (bid < 256) {
        const int row = bid * 32 + (tid >> 3);
        const int b = (bid * 32) >> 11;
        const float* xr = x   + (size_t)row * DIM + (tid & 7) * 64;
        u16*        xo  = x16 + (size_t)row * DIM + (tid & 7) * 64;
        float s = 0.0f;
        #pragma unroll
        for (int j = 0; j < 8; ++j) {
            float4 a = *(const float4*)(xr + j*8);
            float4 c = *(const float4*)(xr + j*8 + 4);
            s += a.x*a.x + a.y*a.y + a.z*a.z + a.w*a.w;
            s += c.x*c.x + c.y*c.y + c.z*c.z + c.w*c.w;
            u16x8 pk;
            pk[0]=f2bf(a.x); pk[1]=f2bf(a.y); pk[2]=f2bf(a.z); pk[3]=f2bf(a.w);
            pk[4]=f2bf(c.x); pk[5]=f2bf(c.y); pk[6]=f2bf(c.z); pk[7]=f2bf(c.w);
            *(u16x8*)(xo + j*8) = pk;
        }
        #pragma unroll
        for (int off = 1; off < 8; off <<= 1) s += __shfl_xor(s, off, 64);
        float m = s;
        #pragma unroll
        for (int off = 8; off < 64; off <<= 1) m = fmaxf(m, __shfl_xor(m, off, 64));
        if ((tid & 63) == 0) red[tid >> 6] = m;
        __syncthreads();
        if (tid == 0) {
            float mx = fmaxf(fmaxf(red[0], red[1]), fmaxf(red[2], red[3]));
            atomicMax(&bmaxsq[b], __float_as_uint(mx));
        }
    } else {
        const float* in; u16* outp; int K, N, tb;
        if (bid < 768) { in = Wqkv; outp = Wtq; K = 512; N = 1024; tb = bid - 256; }
        else           { in = Wproj; outp = Wtp; K = 512; N = 512;  tb = bid - 768; }
        const int ntiles = N >> 5;
        const int bx = tb % ntiles, by = tb / ntiles;
        const int n0 = bx * 32, k0 = by * 32;
        const int tx = tid & 31, ty = tid >> 5;
        #pragma unroll
        for (int i = 0; i < 32; i += 8)
            t[ty + i][tx] = f2bf(in[(size_t)(k0 + ty + i) * N + n0 + tx]);
        __syncthreads();
        #pragma unroll
        for (int i = 0; i < 32; i += 8)
            outp[(size_t)(n0 + ty + i) * K + k0 + tx] = t[tx][ty + i];
    }
}

// ---------------- MFMA GEMM: qkv = x16 @ Wqkv (via Wt [1024][512] bf16)
// v4: dbuf gll16 staging (vmcnt(8)) + LDS-transposed COALESCED epilogue.
__global__ __launch_bounds__(256) void qkv_mfma(
    const u16* __restrict__ x16, const u16* __restrict__ Wt,
    u16* __restrict__ q16, u16* __restrict__ vt16)
{
    const int tid = threadIdx.x, lane = tid & 63, w = tid >> 6;
    const int li = lane & 15, quad = lane >> 4;
    const int mb = blockIdx.x >> 3, nb = blockIdx.x & 7;   // 64 x 8
    const int row0 = mb * 128, n0 = nb * 128;
    const int b = row0 >> 11;
    const int wm = w >> 1, wn = w & 1;

    __shared__ __align__(16) u16 smemq[32768];   // 64KB: staging + epilogue
    u16* as0 = smemq;            // [2][8192] A bufs
    u16* bs0 = smemq + 16384;    // [2][8192] B bufs

    const int rstg = tid >> 3;
    const int cstg = ((tid & 7) ^ (rstg & 7)) * 8;
    const u16* xa = x16 + (size_t)(row0 + rstg) * DIM + cstg;
    const u16* wb = Wt  + (size_t)(n0  + rstg) * DIM + cstg;
    const int ldb = w * 512;                               // wave-uniform base

    const int fs0 = ((quad)     ^ (li & 7)) << 3;
    const int fs1 = ((quad + 4) ^ (li & 7)) << 3;

    auto stage = [&](int bf, int k0) {
        #pragma unroll
        for (int it = 0; it < 4; ++it) {
            gll16(xa + k0 + (size_t)it * 32 * DIM, as0 + bf*8192 + it*2048 + ldb);
            gll16(wb + k0 + (size_t)it * 32 * DIM, bs0 + bf*8192 + it*2048 + ldb);
        }
    };

    f32x4 acc[4][4];
    #pragma unroll
    for (int mi = 0; mi < 4; ++mi)
        #pragma unroll
        for (int ni = 0; ni < 4; ++ni) acc[mi][ni] = f32x4{0.f,0.f,0.f,0.f};

    stage(0, 0);
    for (int ki = 0; ki < 8; ++ki) {
        const int cur = ki & 1;
        if (ki < 7) {
            stage(cur ^ 1, (ki + 1) * 64);
            asm volatile("s_waitcnt vmcnt(8)" ::: "memory");
        } else {
            asm volatile("s_waitcnt vmcnt(0)" ::: "memory");
        }
        __syncthreads();

        bf16x8 af[4][2], bfr[4][2];
        #pragma unroll
        for (int mi = 0; mi < 4; ++mi) {
            const u16* p = &as0[cur*8192 + (wm*64 + mi*16 + li) * 64];
            af[mi][0] = *(const bf16x8*)(p + fs0);
            af[mi][1] = *(const bf16x8*)(p + fs1);
        }
        #pragma unroll
        for (int ni = 0; ni < 4; ++ni) {
            const u16* p = &bs0[cur*8192 + (wn*64 + ni*16 + li) * 64];
            bfr[ni][0] = *(const bf16x8*)(p + fs0);
            bfr[ni][1] = *(const bf16x8*)(p + fs1);
        }
        #pragma unroll
        for (int mi = 0; mi < 4; ++mi)
            #pragma unroll
            for (int ni = 0; ni < 4; ++ni) {
                acc[mi][ni] = __builtin_amdgcn_mfma_f32_16x16x32_bf16(
                    af[mi][0], bfr[ni][0], acc[mi][ni], 0, 0, 0);
                acc[mi][ni] = __builtin_amdgcn_mfma_f32_16x16x32_bf16(
                    af[mi][1], bfr[ni][1], acc[mi][ni], 0, 0, 0);
            }
        __syncthreads();
    }

    // ---- epilogue: acc -> LDS [c_local 128][t 128] bf16 (stride 132) ----
    u16* eps = smemq;   // 128*132*2 = 33792 B, staging fully consumed
    const int cbase = wn*64 + li;
    const int tbase = wm*64 + quad*4;
    #pragma unroll
    for (int ni = 0; ni < 4; ++ni)
        #pragma unroll
        for (int mi = 0; mi < 4; ++mi) {
            union { u32 u[2]; u16x4 v; } pk;
            pk.u[0] = cvtpk(acc[mi][ni][0], acc[mi][ni][1]);
            pk.u[1] = cvtpk(acc[mi][ni][2], acc[mi][ni][3]);
            *(u16x4*)&eps[(cbase + ni*16)*132 + tbase + mi*16] = pk.v;
        }
    __syncthreads();

    const int trow = row0 & (TT-1);
    const int d0 = n0 >> 4;
    // q: c_local = dl*16 + h (k=0). Chunk (h,t): gather 8 u16 -> 16B store.
    #pragma unroll
    for (int it = 0; it < 4; ++it) {
        int id = it*256 + tid;
        int h = id >> 7, t = id & 127;
        union { u16 a[8]; u16x8 v; } ch;
        #pragma unroll
        for (int dl = 0; dl < 8; ++dl)
            ch.a[dl] = eps[(dl*16 + h)*132 + t];
        *(u16x8*)(q16 + ((size_t)(b*NH + h)*TT + trow + t)*HD + d0) = ch.v;
    }
    // v: c_local = dl*16 + 8 + h (k=1). Row-contig LDS -> coalesced 16B.
    #pragma unroll
    for (int it = 0; it < 4; ++it) {
        int id = it*256 + tid;
        int tc = id & 15, dl = (id >> 4) & 7, h = id >> 7;
        union { u16x4 a[2]; u16x8 v; } ch;
        ch.a[0] = *(const u16x4*)&eps[(dl*16 + 8 + h)*132 + tc*8];
        ch.a[1] = *(const u16x4*)&eps[(dl*16 + 8 + h)*132 + tc*8 + 4];
        *(u16x8*)(vt16 + ((size_t)(b*NH + h)*HD + d0 + dl)*TT + trow + tc*8) = ch.v;
    }
}

// ---------------- MFMA GEMM: out(f32) = ao16 @ Wproj + bias(f32)
// v3: N-tile 64 (grid 512 -> 2 blocks/CU), dbuf gll16 staging, vmcnt(6).
__global__ __launch_bounds__(256) void proj_mfma(
    const u16* __restrict__ ao16, const u16* __restrict__ Wt,
    const float* __restrict__ bp, float* __restrict__ out)
{
    const int tid = threadIdx.x, lane = tid & 63, w = tid >> 6;
    const int li = lane & 15, quad = lane >> 4;
    const int mb = blockIdx.x >> 3, nb = blockIdx.x & 7;   // 64 x 8
    const int row0 = mb * 128, n0 = nb * 64;
    const int wm = w >> 1, wn = w & 1;

    __shared__ __align__(16) u16 as[2][128 * 64];
    __shared__ __align__(16) u16 bs[2][64 * 64];

    const int rstg = tid >> 3;
    const int cstg = ((tid & 7) ^ (rstg & 7)) * 8;
    const u16* xa = ao16 + (size_t)(row0 + rstg) * DIM + cstg;
    const u16* wb = Wt   + (size_t)(n0  + rstg) * DIM + cstg;
    const int ldb = w * 512;

    const int fs0 = ((quad)     ^ (li & 7)) << 3;
    const int fs1 = ((quad + 4) ^ (li & 7)) << 3;

    auto stage = [&](int bf, int k0) {
        #pragma unroll
        for (int it = 0; it < 4; ++it)
            gll16(xa + k0 + (size_t)it * 32 * DIM, &as[bf][0] + it * 2048 + ldb);
        #pragma unroll
        for (int it = 0; it < 2; ++it)
            gll16(wb + k0 + (size_t)it * 32 * DIM, &bs[bf][0] + it * 2048 + ldb);
    };

    f32x4 acc[4][2];
    #pragma unroll
    for (int mi = 0; mi < 4; ++mi)
        #pragma unroll
        for (int ni = 0; ni < 2; ++ni) acc[mi][ni] = f32x4{0.f,0.f,0.f,0.f};

    stage(0, 0);
    for (int ki = 0; ki < 8; ++ki) {
        const int cur = ki & 1;
        if (ki < 7) {
            stage(cur ^ 1, (ki + 1) * 64);
            asm volatile("s_waitcnt vmcnt(6)" ::: "memory");
        } else {
            asm volatile("s_waitcnt vmcnt(0)" ::: "memory");
        }
        __syncthreads();

        bf16x8 af[4][2], bfr[2][2];
        #pragma unroll
        for (int mi = 0; mi < 4; ++mi) {
            const u16* p = &as[cur][(wm*64 + mi*16 + li) * 64];
            af[mi][0] = *(const bf16x8*)(p + fs0);
            af[mi][1] = *(const bf16x8*)(p + fs1);
        }
        #pragma unroll
        for (int ni = 0; ni < 2; ++ni) {
            const u16* p = &bs[cur][(wn*32 + ni*16 + li) * 64];
            bfr[ni][0] = *(const bf16x8*)(p + fs0);
            bfr[ni][1] = *(const bf16x8*)(p + fs1);
        }
        #pragma unroll
        for (int mi = 0; mi < 4; ++mi)
            #pragma unroll
            for (int ni = 0; ni < 2; ++ni) {
                acc[mi][ni] = __builtin_amdgcn_mfma_f32_16x16x32_bf16(
                    af[mi][0], bfr[ni][0], acc[mi][ni], 0, 0, 0);
                acc[mi][ni] = __builtin_amdgcn_mfma_f32_16x16x32_bf16(
                    af[mi][1], bfr[ni][1], acc[mi][ni], 0, 0, 0);
            }
        __syncthreads();
    }

    #pragma unroll
    for (int ni = 0; ni < 2; ++ni) {
        int col = n0 + wn*32 + ni*16 + li;
        float bias = bp[col];
        #pragma unroll
        for (int mi = 0; mi < 4; ++mi) {
            int r0 = row0 + wm*64 + mi*16 + quad*4;
            #pragma unroll
            for (int r = 0; r < 4; ++r)
                out[(size_t)(r0 + r)*DIM + col] = acc[mi][ni][r] + bias;
        }
    }
}

// ---------------- qsq: qsq[b,h,t] = sum_d q^2 ; asq[b,h] via 1 atomic/block
__global__ __launch_bounds__(256) void qsq_kernel(
    const u16* __restrict__ q16, float* __restrict__ qsq, float* __restrict__ asq)
{
    const int tid = threadIdx.x;
    const int bh = blockIdx.x >> 3;
    const int r0 = (blockIdx.x & 7) * 256;
    const u16* qb = q16 + ((size_t)bh * TT + r0) * HD;

    float tot = 0.0f;
    #pragma unroll
    for (int i = 0; i < 8; ++i) {
        int row = i * 32 + (tid >> 3);
        u16x8 v = *(const u16x8*)(qb + (size_t)row * HD + (tid & 7) * 8);
        float s = 0.0f;
        #pragma unroll
        for (int j = 0; j < 8; ++j) { float f = bf2f(v[j]); s += f * f; }
        tot += s;
        #pragma unroll
        for (int off = 1; off < 8; off <<= 1) s += __shfl_xor(s, off, 64);
        if ((tid & 7) == 0) qsq[(size_t)bh * TT + r0 + row] = s;
    }
    __shared__ float red[4];
    #pragma unroll
    for (int off = 32; off > 0; off >>= 1) tot += __shfl_down(tot, off, 64);
    if ((tid & 63) == 0) red[tid >> 6] = tot;
    __syncthreads();
    if (tid == 0) atomicAdd(&asq[bh], red[0] + red[1] + red[2] + red[3]);
}

// ---------------- attention v16: v11 + padded combine-overlay stride.
// v11's residual 4.2e6 bank conflicts were ALL in the final flash-combine:
// lane stride 96 f32 = 384B, 384%128==0 -> all 64 lanes in one 4-bank
// group (16-32 way serialization on the once-per-block tail). Stride 100
// (400B, 100/4=25 odd) spreads lanes across all 32 banks. Region 51.2KB
// still fits the 72KB LDS overlay. Main-loop K/V reads already balanced.
__global__ __launch_bounds__(256, 2) void attn_kernel(
    const u16* __restrict__ q16, const u16* __restrict__ vt16,
    const float* __restrict__ qsq, const float* __restrict__ asq,
    const u32* __restrict__ bmaxsq, u16* __restrict__ ao16)
{
    const int tid = threadIdx.x;
    const int lane = tid & 63, w = tid >> 6;          // 4 waves
    const int l31 = lane & 31, hf = lane >> 5;
    const int l7 = lane & 7;
    const int ws = w & 1;                             // s-parity within pair
    const int p  = w >> 1;                            // q-pair (rows p*64..)
    const int bid = blockIdx.x;
    const int bh = (bid & 7) * 4 + (bid >> 7);        // XCD-grouped bh
    const int qtile = (bid >> 3) & 15;
    const int b = bh >> 3, head = bh & 7;

    // smem carve: 4 K bufs (32KB) | 4 V bufs (32KB) | cq (8KB)  = 72KB
    __shared__ __align__(16) u16 smem[36864];
    u16* ksA = smem;                 // [4][64*64] swizzled K [s][d]
    u16* vtA = smem + 16384;         // [4][64*64] swizzled V^T [d][s]
    float* cq = (float*)(smem + 32768);   // cf * qsq[s], s in [0,2048)

    const u16* qgp = q16  + (size_t)bh * TT * HD;     // [t][d]
    const u16* vgp = vt16 + (size_t)bh * HD * TT;     // [d][t]
    const float* qsqg = qsq + (size_t)bh * TT;

    float cf;   // 100 * log2(e) / (a * bmax + eps)
    {
        float a  = sqrtf(asq[bh]);
        float bm = sqrtf(__uint_as_float(bmaxsq[b]));
        cf = (100.0f * 1.44269504089f) / (a * bm + 1e-10f);
    }
    const float c2 = 2.0f * cf;

    // Q B-frags for 2 row-groups: lane holds Q[t=qt0+qg*32+l31][kc*16+hf*8+i]
    const int qt0 = qtile * 128 + p * 64;
    bf16x8 qf[2][4];
    #pragma unroll
    for (int qg = 0; qg < 2; ++qg) {
        const u16* qrow = qgp + (size_t)(qt0 + qg*32 + l31) * HD + hf * 8;
        #pragma unroll
        for (int kc = 0; kc < 4; ++kc)
            qf[qg][kc] = *(const bf16x8*)(qrow + kc * 16);
    }

    // cq staging regs (8 floats per thread)
    const int ci = tid * 8;
    f32x4 cqa = *(const f32x4*)(qsqg + ci);
    f32x4 cqb = *(const f32x4*)(qsqg + ci + 4);

    // swizzled slot offsets (elements): slot kc = ((2*kc + hf) ^ l7)*8
    int slot[4];
    #pragma unroll
    for (int kc = 0; kc < 4; ++kc) slot[kc] = (((2*kc + hf) ^ l7) << 3);

    // staging addresses (inverse-swizzled global source, linear LDS dest)
    const int rk = tid >> 3;
    const int ck = (tid & 7) ^ (rk & 7);
    const u16* kstg = qgp + (size_t)rk * HD + ck * 8;  // + t*64*HD per tile
    const u16* vstg = vgp + (size_t)rk * TT + ck * 8;  // + t*64 per tile
    const int lb0 = w * 512;                           // wave-uniform LDS base
    const int lb1 = 2048 + w * 512;

    // stage a PAIR of tiles {t0g, t0g+1} into ring slots {sb, sb+1}
    auto stagePair = [&](int sb, int t0g) {
        #pragma unroll
        for (int ts = 0; ts < 2; ++ts) {
            const u16* kp = kstg + (size_t)(t0g + ts) * 64 * HD;
            const u16* vp = vstg + (t0g + ts) * 64;
            u16* kb = ksA + (sb + ts) * 4096;
            u16* vb = vtA + (sb + ts) * 4096;
            gll16(kp,                 kb + lb0);
            gll16(kp + 32 * HD,       kb + lb1);
            gll16(vp,                 vb + lb0);
            gll16(vp + (size_t)32*TT, vb + lb1);
        }
    };

    // ones B-frag for denominator MFMA
    bf16x8 onesf;
    {
        union { u16 a[8]; bf16x8 v; } o;
        #pragma unroll
        for (int i = 0; i < 8; ++i) o.a[i] = 0x3F80;
        onesf = o.v;
    }

    f32x16 oacc[2][2], osum[2];
    #pragma unroll
    for (int qg = 0; qg < 2; ++qg) {
        #pragma unroll
        for (int r = 0; r < 16; ++r) { oacc[qg][0][r] = 0.f; oacc[qg][1][r] = 0.f; osum[qg][r] = 0.f; }
    }

    auto tile_compute = [&](const u16* __restrict__ ksb,
                            const u16* __restrict__ vtb, int s0) {
        bf16x8 pa[2][4];
        #pragma unroll
        for (int sc = 0; sc < 2; ++sc) {
            const u16* kbase = ksb + sc * 2048 + l31 * 64;
            bf16x8 kf0 = *(const bf16x8*)(kbase + slot[0]);
            bf16x8 kf1 = *(const bf16x8*)(kbase + slot[1]);
            bf16x8 kf2 = *(const bf16x8*)(kbase + slot[2]);
            bf16x8 kf3 = *(const bf16x8*)(kbase + slot[3]);
            f32x4 cq4[4];
            #pragma unroll
            for (int g = 0; g < 4; ++g)
                cq4[g] = *(const f32x4*)&cq[s0 + sc*32 + g*8 + hf*4];
            #pragma unroll
            for (int qg = 0; qg < 2; ++qg) {
                f32x16 acc;
                #pragma unroll
                for (int r = 0; r < 16; ++r) acc[r] = 0.0f;
                __builtin_amdgcn_s_setprio(1);
                acc = __builtin_amdgcn_mfma_f32_32x32x16_bf16(kf0, qf[qg][0], acc, 0, 0, 0);
                acc = __builtin_amdgcn_mfma_f32_32x32x16_bf16(kf1, qf[qg][1], acc, 0, 0, 0);
                acc = __builtin_amdgcn_mfma_f32_32x32x16_bf16(kf2, qf[qg][2], acc, 0, 0, 0);
                acc = __builtin_amdgcn_mfma_f32_32x32x16_bf16(kf3, qf[qg][3], acc, 0, 0, 0);
                __builtin_amdgcn_s_setprio(0);
                float pv[16];
                #pragma unroll
                for (int g = 0; g < 4; ++g) {
                    pv[4*g+0] = __builtin_amdgcn_exp2f(fmaf(c2, acc[4*g+0], -cq4[g][0]));
                    pv[4*g+1] = __builtin_amdgcn_exp2f(fmaf(c2, acc[4*g+1], -cq4[g][1]));
                    pv[4*g+2] = __builtin_amdgcn_exp2f(fmaf(c2, acc[4*g+2], -cq4[g][2]));
                    pv[4*g+3] = __builtin_amdgcn_exp2f(fmaf(c2, acc[4*g+3], -cq4[g][3]));
                }
                #pragma unroll
                for (int kh = 0; kh < 2; ++kh) {
                    u32 A0 = cvtpk(pv[8*kh+0], pv[8*kh+1]);
                    u32 B0 = cvtpk(pv[8*kh+4], pv[8*kh+5]);
                    u32 A1 = cvtpk(pv[8*kh+2], pv[8*kh+3]);
                    u32 B1 = cvtpk(pv[8*kh+6], pv[8*kh+7]);
                    u32x2 r0 = __builtin_amdgcn_permlane32_swap(A0, B0, false, false);
                    u32x2 r1 = __builtin_amdgcn_permlane32_swap(A1, B1, false, false);
                    union { u32 u[4]; bf16x8 v; } pw;
                    pw.u[0] = r0.x; pw.u[1] = r1.x; pw.u[2] = r0.y; pw.u[3] = r1.y;
                    pa[qg][sc*2 + kh] = pw.v;
                }
            }
        }
        // PV + denominator: each V frag feeds 2 qg; ones-MFMA row-sums P
        #pragma unroll
        for (int kc = 0; kc < 4; ++kc) {
            bf16x8 vf0 = *(const bf16x8*)(vtb + (0*32 + l31) * 64 + slot[kc]);
            bf16x8 vf1 = *(const bf16x8*)(vtb + (1*32 + l31) * 64 + slot[kc]);
            __builtin_amdgcn_s_setprio(1);
            #pragma unroll
            for (int qg = 0; qg < 2; ++qg) {
                oacc[qg][0] = __builtin_amdgcn_mfma_f32_32x32x16_bf16(
                    pa[qg][kc], vf0, oacc[qg][0], 0, 0, 0);
                oacc[qg][1] = __builtin_amdgcn_mfma_f32_32x32x16_bf16(
                    pa[qg][kc], vf1, oacc[qg][1], 0, 0, 0);
                osum[qg] = __builtin_amdgcn_mfma_f32_32x32x16_bf16(
                    pa[qg][kc], onesf, osum[qg], 0, 0, 0);
            }
            __builtin_amdgcn_s_setprio(0);
        }
    };

    // prologue: stage pairs 0,1 (tiles 0..3); cq table
    stagePair(0, 0);
    stagePair(2, 2);
    *(f32x4*)&cq[ci]     = cqa * cf;
    *(f32x4*)&cq[ci + 4] = cqb * cf;
    asm volatile("s_waitcnt lgkmcnt(0)" ::: "memory");
    __builtin_amdgcn_s_barrier();

    // 16 pairs of tiles; wave computes tile 2m+ws of pair m
    #pragma unroll 2
    for (int m = 0; m < 15; ++m) {
        asm volatile("s_waitcnt vmcnt(8)" ::: "memory");
        __builtin_amdgcn_s_barrier();
        const int sb = (m & 1) * 2;
        tile_compute(ksA + (sb + ws) * 4096, vtA + (sb + ws) * 4096,
                     (2*m + ws) * 64);
        __builtin_amdgcn_s_barrier();
        if (m <= 13) stagePair(sb, 2*(m + 2));
    }
    asm volatile("s_waitcnt vmcnt(0)" ::: "memory");
    __builtin_amdgcn_s_barrier();
    tile_compute(ksA + (2 + ws) * 4096, vtA + (2 + ws) * 4096,
                 (30 + ws) * 64);
    __builtin_amdgcn_s_barrier();   // all reads done before combine overlay

    // flash combine across the s-split wave pair (overlay K/V ring).
    // stride 100 f32 (400B, odd dword multiple) -> conflict-free banks.
    float* cmb = (float*)smem;      // per pair: 64 lanes x 100 f32 = 25.6KB
    float* myc = cmb + p * 6400 + lane * 100;
    if (ws == 1) {
        #pragma unroll
        for (int qg = 0; qg < 2; ++qg) {
            #pragma unroll
            for (int dh = 0; dh < 2; ++dh)
                #pragma unroll
                for (int v4 = 0; v4 < 4; ++v4)
                    *(f32x4*)(myc + (qg*2 + dh)*16 + v4*4) =
                        f32x4{oacc[qg][dh][v4*4+0], oacc[qg][dh][v4*4+1],
                              oacc[qg][dh][v4*4+2], oacc[qg][dh][v4*4+3]};
            #pragma unroll
            for (int v4 = 0; v4 < 4; ++v4)
                *(f32x4*)(myc + 64 + qg*16 + v4*4) =
                    f32x4{osum[qg][v4*4+0], osum[qg][v4*4+1],
                          osum[qg][v4*4+2], osum[qg][v4*4+3]};
        }
    }
    asm volatile("s_waitcnt lgkmcnt(0)" ::: "memory");
    __builtin_amdgcn_s_barrier();
    if (ws == 0) {
        #pragma unroll
        for (int qg = 0; qg < 2; ++qg) {
            #pragma unroll
            for (int dh = 0; dh < 2; ++dh)
                #pragma unroll
                for (int r = 0; r < 16; ++r)
                    oacc[qg][dh][r] += myc[(qg*2 + dh)*16 + r];
            #pragma unroll
            for (int r = 0; r < 16; ++r)
                osum[qg][r] += myc[64 + qg*16 + r];
        }
        // O rows: t = qt0 + qg*32 + (reg&3) + 8*(reg>>2) + 4*hf; col d = dh*32+l31
        #pragma unroll
        for (int qg = 0; qg < 2; ++qg) {
            float inv[16];
            #pragma unroll
            for (int r = 0; r < 16; ++r) inv[r] = 1.0f / osum[qg][r];
            #pragma unroll
            for (int dh = 0; dh < 2; ++dh)
                #pragma unroll
                for (int g = 0; g < 4; ++g)
                    #pragma unroll
                    for (int r0 = 0; r0 < 4; ++r0) {
                        int t = qt0 + qg*32 + g*8 + hf*4 + r0;
                        ao16[((size_t)(b*TT + t))*DIM + head*HD + dh*32 + l31] =
                            f2bf(oacc[qg][dh][g*4 + r0] * inv[g*4 + r0]);
                    }
        }
    }
}

extern "C" void kernel_launch(void* const* d_in, const int* in_sizes, int n_in,
                              void* d_out, int out_size, void* d_ws, size_t ws_size,
                              hipStream_t stream)
{
    const float* x     = (const float*)d_in[0];   // [4,2048,512] f32
    const float* Wqkv  = (const float*)d_in[1];   // [512,1024]  f32
    const float* Wproj = (const float*)d_in[2];   // [512,512]   f32
    const float* bproj = (const float*)d_in[3];   // [512]       f32
    float* out = (float*)d_out;                   // [4,2048,512] f32

    char* ws = (char*)d_ws;
    const size_t MB = 1024*1024;
    u16*   q16  = (u16*)(ws);                          // 8 MB  [b,h,t,d] bf16
    u16*   vt16 = (u16*)(ws + 8*MB);                   // 8 MB  [b,h,d,t] bf16
    u16*   ao16 = (u16*)(ws + 16*MB);                  // 8 MB  [b,t,dim] bf16
    u16*   x16  = (u16*)(ws + 24*MB);                  // 8 MB  [b,t,dim] bf16
    u16*   Wtq  = (u16*)(ws + 32*MB);                  // 1 MB  [1024][512]
    u16*   Wtp  = (u16*)(ws + 33*MB);                  // 0.5MB [512][512]
    float* qsq  = (float*)(ws + 34*MB);                // 256 KB (16B aligned)
    float* asq  = (float*)(ws + 34*MB + 262144);       // 128 B
    u32* bmaxsq = (u32*)(ws + 34*MB + 262144 + 128);   // 16 B

    (void)in_sizes; (void)n_in; (void)out_size; (void)ws_size;

    hipMemsetAsync(ws + 34*MB + 262144, 0, 144, stream);

    prep_kernel<<<1024, 256, 0, stream>>>(x, x16, bmaxsq, Wqkv, Wtq, Wproj, Wtp);

    qkv_mfma<<<64*8, 256, 0, stream>>>(x16, Wtq, q16, vt16);

    qsq_kernel<<<BH*8, 256, 0, stream>>>(q16, qsq, asq);

    attn_kernel<<<BH*16, 256, 0, stream>>>(q16, vt16, qsq, asq, bmaxsq, ao16);

    proj_mfma<<<64*8, 256, 0, stream>>>(ao16, Wtp, bproj, out);
}